// Round 17
// baseline (497.351 us; speedup 1.0000x reference)
//
#include <hip/hip_runtime.h>
#include <stdint.h>

#define HIDDEN 1024
#define INTER  4096
#define NTOK   4096
#define HROWS  (2*NTOK)
#define MAXB   72            // max 128-row blocks (mlp1: 32 shared + experts)
#define MAXB2  40            // max expert-only 128-row blocks (mlp2)
#define NMAT   27            // 0..8: w1s,W1[0..7]; 9..17: w2s,W2; 18..26: w3s,W3

typedef unsigned short u16;
typedef unsigned int   u32;
typedef __bf16  bf16x8 __attribute__((ext_vector_type(8)));
typedef float   f32x4  __attribute__((ext_vector_type(4)));
typedef u32     u32x4  __attribute__((ext_vector_type(4)));

#define WAITVM(N) asm volatile("s_waitcnt vmcnt(" #N ")" ::: "memory")

__device__ __forceinline__ void hard_barrier() {
  asm volatile("" ::: "memory");
  __builtin_amdgcn_s_barrier();
  asm volatile("" ::: "memory");
}

__device__ __forceinline__ u16 f2bf(float f) {
  u32 u = __float_as_uint(f);
  u32 r = u + 0x7FFFu + ((u >> 16) & 1u);
  return (u16)(r >> 16);
}

__device__ __forceinline__ u32 cvt_pk_bf16(float lo, float hi) {
  u32 r;
  asm("v_cvt_pk_bf16_f32 %0, %1, %2" : "=v"(r) : "v"(lo), "v"(hi));
  return r;
}

__device__ __forceinline__ void glds16(const void* g, void* l) {
  __builtin_amdgcn_global_load_lds(
      (const __attribute__((address_space(1))) void*)g,
      (__attribute__((address_space(3))) void*)l, 16, 0, 0);
}

__device__ __forceinline__ f32x4 ntload4(const float* p) {
  return __builtin_nontemporal_load((const f32x4*)p);
}

// m204 bijective XCD swizzle: consecutive virt ids -> one XCD's contiguous chunk.
__device__ __forceinline__ int xcd_swz(int orig, int T) {
  int q = T >> 3, r = T & 7;
  int xcd = orig & 7, pos = orig >> 3;
  return (xcd < r ? xcd * (q + 1) : r * (q + 1) + (xcd - r) * q) + pos;
}

// (g, hrow0, rows, pb) for mlp1 block bx (32 shared blocks + expert blocks).
__device__ __forceinline__ void blk_entry(const int* cnts, int bx,
                                          int& g, int& hrow0, int& rows, int& pb) {
  if (bx < 32) { g = 8; hrow0 = bx * 128; rows = 128; pb = 0; return; }
  int b = bx - 32, o = 0; g = -1;
  #pragma unroll
  for (int e = 0; e < 8; ++e) {
    int ne = (cnts[e] + 127) >> 7;
    if (g < 0) {
      if (b < ne) {
        g = e; pb = o + b * 128;
        rows = cnts[e] - b * 128; if (rows > 128) rows = 128;
        hrow0 = NTOK + pb;
      } else b -= ne;
    }
    o += cnts[e];
  }
}

// (g, rows, pb) for mlp2 expert-only block bx.
__device__ __forceinline__ void blk_entry_exp(const int* cnts, int bx,
                                              int& g, int& rows, int& pb) {
  int b = bx, o = 0; g = -1;
  #pragma unroll
  for (int e = 0; e < 8; ++e) {
    int ne = (cnts[e] + 127) >> 7;
    if (g < 0) {
      if (b < ne) {
        g = e; pb = o + b * 128;
        rows = cnts[e] - b * 128; if (rows > 128) rows = 128;
      } else b -= ne;
    }
    o += cnts[e];
  }
}

// ---------------- k_pre: weight precvt (blocks < NMAT*512) + gate/x-cvt (rest) ----------
// wcvt: fp32 [K][N] -> bf16 pre-swizzled 8KB BK=32 panels (two per block).
// Panel (m, cp, kt): [128 n][32 k] bf16; u16 off n*32 + s*8 + (k&7), slot s holds
// k-chunk (s ^ ((n>>1)&3)). pidx = m*1024 + cp*NKT + kt (w1/w2: NKT=32; w3: NKT=128).
// fp32 reads NONTEMPORAL; measured floor ~2.7 TB/s for this stream (R15/R16 A/B).

__global__ __launch_bounds__(256) void k_pre(
    const float* __restrict__ w1s, const float* __restrict__ w2s,
    const float* __restrict__ w3s, const float* __restrict__ W1,
    const float* __restrict__ W2,  const float* __restrict__ W3,
    u16* __restrict__ Wb,
    const float* __restrict__ x,   const float* __restrict__ wg,
    int* __restrict__ idx, int* __restrict__ cnt, u16* __restrict__ xb)
{
  __shared__ float tileF[32 * 256];
  int tid = threadIdx.x;

  if (blockIdx.x < NMAT * 512) {
    // ---- weight conversion ----
    int bid = blockIdx.x;
    int m = bid >> 9, pair = bid & 511;
    const float* src; int N, nkt, kt, pp2;
    if (m < 18) {
      N = INTER; nkt = 32;
      int mm = (m < 9) ? m : m - 9;
      const float* sp = (m < 9) ? w1s : w2s;
      const float* ep = (m < 9) ? W1 : W2;
      src = (mm == 0) ? sp : ep + (size_t)(mm - 1) * HIDDEN * INTER;
      kt = pair >> 4; pp2 = pair & 15;
    } else {
      N = HIDDEN; nkt = 128;
      int mm = m - 18;
      src = (mm == 0) ? w3s : W3 + (size_t)(mm - 1) * INTER * HIDDEN;
      kt = pair >> 2; pp2 = pair & 3;
    }

    const float* in0 = src + (size_t)(kt * 32) * N + pp2 * 256;
    #pragma unroll
    for (int i = 0; i < 8; ++i) {
      int f = tid + 256 * i;          // float4 index within 32x256 tile
      int k = f >> 6, c4 = f & 63;
      *(f32x4*)&tileF[k * 256 + c4 * 4] = ntload4(in0 + (size_t)k * N + c4 * 4);
    }
    __syncthreads();

    int p2 = tid >> 7, n = tid & 127;
    int pidx = m * 1024 + (pp2 * 2 + p2) * nkt + kt;
    u16* outp = Wb + (size_t)pidx * 4096 + n * 32;
    #pragma unroll
    for (int s = 0; s < 4; ++s) {
      int k8 = s ^ ((n >> 1) & 3);
      const float* col = &tileF[(k8 * 8) * 256 + p2 * 128 + n];
      u32x4 pk;
      pk.x = cvt_pk_bf16(col[0],    col[256]);
      pk.y = cvt_pk_bf16(col[512],  col[768]);
      pk.z = cvt_pk_bf16(col[1024], col[1280]);
      pk.w = cvt_pk_bf16(col[1536], col[1792]);
      *(u32x4*)(outp + s * 8) = pk;
    }
  } else {
    // ---- gate + x->bf16 (vectorized) ----
    int gb = blockIdx.x - NMAT * 512;
    int wave = tid >> 6, lane = tid & 63;
    int t = gb * 4 + wave;
    if (t >= NTOK) return;
    float acc[8];
    #pragma unroll
    for (int e = 0; e < 8; ++e) acc[e] = 0.f;
    const float* xr = x + (size_t)t * HIDDEN;
    u16* xbr = xb + (size_t)t * HIDDEN;
    #pragma unroll
    for (int it = 0; it < HIDDEN / 4 / 64; ++it) {   // 4 iterations
      int c4i = it * 64 + lane;
      f32x4 xv = *(const f32x4*)(xr + c4i * 4);
      ushort4 o;
      o.x = f2bf(xv.x); o.y = f2bf(xv.y); o.z = f2bf(xv.z); o.w = f2bf(xv.w);
      *(ushort4*)(xbr + c4i * 4) = o;
      const float* wr = wg + (size_t)c4i * 32;       // 4 rows of 8
      #pragma unroll
      for (int u = 0; u < 4; ++u)
        #pragma unroll
        for (int e = 0; e < 8; ++e) acc[e] += xv[u] * wr[u * 8 + e];
    }
    #pragma unroll
    for (int e = 0; e < 8; ++e)
      for (int s = 32; s; s >>= 1) acc[e] += __shfl_xor(acc[e], s);
    if (lane == 0) {
      int best = 0; float bv = acc[0];
      #pragma unroll
      for (int e = 1; e < 8; ++e) if (acc[e] > bv) { bv = acc[e]; best = e; }
      idx[t] = best;
      atomicAdd(&cnt[best], 1);
    }
  }
}

__global__ void k_scatter(const int* __restrict__ idx, const int* __restrict__ cnt,
                          int* __restrict__ fill, int* __restrict__ perm) {
  int t = blockIdx.x * blockDim.x + threadIdx.x;
  if (t >= NTOK) return;
  int e = idx[t];
  int off = 0;
  #pragma unroll
  for (int j = 0; j < 8; ++j) off += (j < e) ? cnt[j] : 0;
  int p = atomicAdd(&fill[e], 1);
  perm[off + p] = t;
}

// ---------------- stage 1: H = gelu(Xg@W1) * (Xg@W2) ----------------
// Best measured structure: 128x(128 dual) tile, 4 waves (2M x 2N), 256 threads,
// BK=32, 3 x 24KB LDS -> 2 blocks/CU, depth-2 prefetch, counted WAITVM(6),
// 1D grid with pp-major XCD swizzle (T1), nontemporal Hbuf stores.
// Per buffer: A [0,8K), B1 [8K,16K), B2 [16K,24K).

#define M1_TILE(B, STG, WN)                                                          \
  do {                                                                               \
    const u16* LA = pAr  + (B) * 12288;                                              \
    const u16* L1 = pBr1 + (B) * 12288;                                              \
    const u16* L2 = pBr2 + (B) * 12288;                                              \
    if (STG) {                                                                       \
      char* Ld = smem + (((B) + 2) % 3) * 24576;                                     \
      glds16(srcA0, Ld + w * 2048);                                                  \
      glds16(srcA1, Ld + w * 2048 + 1024);                                           \
      glds16(srcB1, Ld + 8192 + w * 2048);                                           \
      glds16(srcB1 + 1024, Ld + 8192 + w * 2048 + 1024);                             \
      glds16(srcB2, Ld + 16384 + w * 2048);                                          \
      glds16(srcB2 + 1024, Ld + 16384 + w * 2048 + 1024);                            \
      srcA0 += 64; srcA1 += 64; srcB1 += 8192; srcB2 += 8192;                        \
    }                                                                                \
    bf16x8 af[4], b1[4], b2[4];                                                      \
    _Pragma("unroll")                                                                \
    for (int mi = 0; mi < 4; ++mi) af[mi] = *(const bf16x8*)(LA + mi * 512);         \
    _Pragma("unroll")                                                                \
    for (int ni = 0; ni < 4; ++ni) {                                                 \
      b1[ni] = *(const bf16x8*)(L1 + ni * 512);                                      \
      b2[ni] = *(const bf16x8*)(L2 + ni * 512);                                      \
    }                                                                                \
    __builtin_amdgcn_s_setprio(1);                                                   \
    _Pragma("unroll")                                                                \
    for (int mi = 0; mi < 4; ++mi)                                                   \
      _Pragma("unroll")                                                              \
      for (int ni = 0; ni < 4; ++ni) {                                               \
        acc1[mi][ni] = __builtin_amdgcn_mfma_f32_16x16x32_bf16(af[mi], b1[ni], acc1[mi][ni], 0, 0, 0); \
        acc2[mi][ni] = __builtin_amdgcn_mfma_f32_16x16x32_bf16(af[mi], b2[ni], acc2[mi][ni], 0, 0, 0); \
      }                                                                              \
    __builtin_amdgcn_s_setprio(0);                                                   \
    WN;                                                                              \
    hard_barrier();                                                                  \
  } while (0)

__global__ __launch_bounds__(256, 2) void k_mlp1(
    const u16* __restrict__ xb, const u16* __restrict__ Wb,
    const int* __restrict__ perm, const int* __restrict__ cnt,
    u16* __restrict__ Hbuf)
{
  int cnts[8];
  #pragma unroll
  for (int e = 0; e < 8; ++e) cnts[e] = cnt[e];
  int nb = 32;
  #pragma unroll
  for (int e = 0; e < 8; ++e) nb += (cnts[e] + 127) >> 7;
  int T = nb * 32;
  int lid = blockIdx.x;
  if (lid >= T) return;
  int virt = xcd_swz(lid, T);
  int pp = virt / nb;             // 0..31 (B column-panel)
  int bx = virt - pp * nb;        // row-block

  int g, hrow0, rows, pb;
  blk_entry(cnts, bx, g, hrow0, rows, pb);
  int m1 = (g == 8) ? 0 : 1 + g;
  int nbase = pp * 128;

  extern __shared__ __align__(16) char smem[];
  int tid = threadIdx.x;
  int w = tid >> 6, lane = tid & 63;
  int q = lane >> 4, rl = lane & 15;
  int mw = w >> 1, nw = w & 1;

  int tokj[2];
  #pragma unroll
  for (int j = 0; j < 2; ++j) {
    int r = w * 32 + j * 16 + (lane >> 2);
    int rc = (r < rows) ? r : (rows - 1);
    tokj[j] = (g == 8) ? (hrow0 + rc) : perm[pb + rc];
  }
  int gch = ((lane & 3) ^ ((lane >> 3) & 3)) * 16;   // pre-swizzled A source chunk

  const char* srcA0 = (const char*)xb + (size_t)tokj[0] * 2048 + gch;
  const char* srcA1 = (const char*)xb + (size_t)tokj[1] * 2048 + gch;
  const char* srcB1 = (const char*)Wb + ((size_t)m1 * 1024 + pp * 32) * 8192 + w * 2048 + (lane << 4);
  const char* srcB2 = (const char*)Wb + ((size_t)(m1 + 9) * 1024 + pp * 32) * 8192 + w * 2048 + (lane << 4);

  int co = (q ^ ((rl >> 1) & 3)) * 8;
  const u16* pAr  = (const u16*)smem + (mw * 64 + rl) * 32 + co;
  const u16* pBr1 = (const u16*)smem + 4096 + (nw * 64 + rl) * 32 + co;
  const u16* pBr2 = (const u16*)smem + 8192 + (nw * 64 + rl) * 32 + co;

  f32x4 acc1[4][4], acc2[4][4];
  f32x4 z = {0.f, 0.f, 0.f, 0.f};
  #pragma unroll
  for (int mi = 0; mi < 4; ++mi)
    #pragma unroll
    for (int ni = 0; ni < 4; ++ni) { acc1[mi][ni] = z; acc2[mi][ni] = z; }

  // prologue: stage tiles 0,1 (6 glds/wave each)
  #pragma unroll
  for (int p = 0; p < 2; ++p) {
    char* Ld = smem + p * 24576;
    glds16(srcA0, Ld + w * 2048);
    glds16(srcA1, Ld + w * 2048 + 1024);
    glds16(srcB1, Ld + 8192 + w * 2048);
    glds16(srcB1 + 1024, Ld + 8192 + w * 2048 + 1024);
    glds16(srcB2, Ld + 16384 + w * 2048);
    glds16(srcB2 + 1024, Ld + 16384 + w * 2048 + 1024);
    srcA0 += 64; srcA1 += 64; srcB1 += 8192; srcB2 += 8192;
  }
  WAITVM(6);           // 12 out -> tile 0 complete
  hard_barrier();

  // NT = 32: tiles 0..29 stage(t+2); tail 30,31
  for (int r = 0; r < 10; ++r) {
    M1_TILE(0, 1, WAITVM(6));
    M1_TILE(1, 1, WAITVM(6));
    M1_TILE(2, 1, WAITVM(6));
  }
  M1_TILE(0, 0, WAITVM(0));   // t=30
  M1_TILE(1, 0, (void)0);     // t=31

  #pragma unroll
  for (int mi = 0; mi < 4; ++mi) {
    #pragma unroll
    for (int j = 0; j < 4; ++j) {
      int r = mw * 64 + mi * 16 + q * 4 + j;
      if (r < rows) {
        size_t hb = (size_t)(hrow0 + r) * INTER + nbase + nw * 64;
        #pragma unroll
        for (int ni = 0; ni < 4; ++ni) {
          float h1 = acc1[mi][ni][j];
          float h2 = acc2[mi][ni][j];
          float ge = 0.5f * h1 * (1.0f + erff(h1 * 0.7071067811865476f));
          __builtin_nontemporal_store(f2bf(ge * h2), &Hbuf[hb + ni * 16 + rl]);
        }
      }
    }
  }
}

// ---------------- stage 2: out = H_shared @ w3s + H_exp @ W3[e] (fused K=8192) ----------------
// Expert-grouped blocks only; 128x128 tile, 4 waves, 256 threads, BK=32,
// 3 x 16KB LDS -> 3 blocks/CU, depth-2 prefetch, counted WAITVM(4), XCD swizzle.
// K-phase 1 (tiles 0..127): A = shared H rows (token-gathered), B = w3s panels.
// K-phase 2 (tiles 128..255): A = expert H rows, B = W3[e] panels (pointer switch).
// Single direct nontemporal store to out — no yexp, no k_add.

#define M2_TILE(B, STG, WN)                                                          \
  do {                                                                               \
    const u16* LA = pAr + (B) * 8192;                                                \
    const u16* LB = pBr + (B) * 8192;                                                \
    if (STG) {                                                                       \
      char* Ld = smem + (((B) + 2) % 3) * 16384;                                     \
      glds16(srcA0, Ld + w * 2048);                                                  \
      glds16(srcA1, Ld + w * 2048 + 1024);                                           \
      glds16(srcB0, Ld + 8192 + w * 2048);                                           \
      glds16(srcB0 + 1024, Ld + 8192 + w * 2048 + 1024);                             \
      srcA0 += 64; srcA1 += 64; srcB0 += 8192;                                       \
    }                                                                                \
    bf16x8 af[4], bf[4];                                                             \
    _Pragma("unroll")                                                                \
    for (int mi = 0; mi < 4; ++mi) af[mi] = *(const bf16x8*)(LA + mi * 512);         \
    _Pragma("unroll")                                                                \
    for (int ni = 0; ni < 4; ++ni) bf[ni] = *(const bf16x8*)(LB + ni * 512);         \
    __builtin_amdgcn_s_setprio(1);                                                   \
    _Pragma("unroll")                                                                \
    for (int mi = 0; mi < 4; ++mi)                                                   \
      _Pragma("unroll")                                                              \
      for (int ni = 0; ni < 4; ++ni)                                                 \
        acc[mi][ni] = __builtin_amdgcn_mfma_f32_16x16x32_bf16(af[mi], bf[ni], acc[mi][ni], 0, 0, 0); \
    __builtin_amdgcn_s_setprio(0);                                                   \
    WN;                                                                              \
    hard_barrier();                                                                  \
  } while (0)

__global__ __launch_bounds__(256, 3) void k_mlp2(
    const u16* __restrict__ Hbuf, const u16* __restrict__ Wb,
    const int* __restrict__ perm, const int* __restrict__ cnt,
    float* __restrict__ out)
{
  int cnts[8];
  #pragma unroll
  for (int e = 0; e < 8; ++e) cnts[e] = cnt[e];
  int nb = 0;
  #pragma unroll
  for (int e = 0; e < 8; ++e) nb += (cnts[e] + 127) >> 7;
  int T = nb * 8;
  int lid = blockIdx.x;
  if (lid >= T) return;
  int virt = xcd_swz(lid, T);
  int pp = virt / nb;             // 0..7
  int bx = virt - pp * nb;

  int g, rows, pb;
  blk_entry_exp(cnts, bx, g, rows, pb);
  int nbase = pp * 128;

  extern __shared__ __align__(16) char smem[];
  int tid = threadIdx.x;
  int w = tid >> 6, lane = tid & 63;
  int q = lane >> 4, rl = lane & 15;
  int mw = w >> 1, nw = w & 1;

  int tokj[2], rcj[2];
  #pragma unroll
  for (int j = 0; j < 2; ++j) {
    int r = w * 32 + j * 16 + (lane >> 2);
    int rc = (r < rows) ? r : (rows - 1);
    rcj[j] = rc;
    tokj[j] = perm[pb + rc];
  }
  int gch = ((lane & 3) ^ ((lane >> 3) & 3)) * 16;

  // phase-1 staging pointers: shared H rows (token-gathered) + w3s panels
  const char* srcA0 = (const char*)Hbuf + (size_t)tokj[0] * (INTER * 2) + gch;
  const char* srcA1 = (const char*)Hbuf + (size_t)tokj[1] * (INTER * 2) + gch;
  const char* srcB0 = (const char*)Wb + ((size_t)18 * 1024 + pp * 128) * 8192 + w * 2048 + (lane << 4);

  int co = (q ^ ((rl >> 1) & 3)) * 8;
  const u16* pAr = (const u16*)smem + (mw * 64 + rl) * 32 + co;
  const u16* pBr = (const u16*)smem + 4096 + (nw * 64 + rl) * 32 + co;

  f32x4 acc[4][4];
  f32x4 z = {0.f, 0.f, 0.f, 0.f};
  #pragma unroll
  for (int mi = 0; mi < 4; ++mi)
    #pragma unroll
    for (int ni = 0; ni < 4; ++ni) acc[mi][ni] = z;

  // prologue: stage tiles 0,1 (4 glds/wave each)
  #pragma unroll
  for (int p = 0; p < 2; ++p) {
    char* Ld = smem + p * 16384;
    glds16(srcA0, Ld + w * 2048);
    glds16(srcA1, Ld + w * 2048 + 1024);
    glds16(srcB0, Ld + 8192 + w * 2048);
    glds16(srcB0 + 1024, Ld + 8192 + w * 2048 + 1024);
    srcA0 += 64; srcA1 += 64; srcB0 += 8192;
  }
  WAITVM(4);           // 8 out -> tile 0 complete
  hard_barrier();

  // ---- K-phase 1: tiles 0..125 (stage t+2 <= 127, shared region) ----
  for (int r = 0; r < 42; ++r) {
    M2_TILE(0, 1, WAITVM(4));
    M2_TILE(1, 1, WAITVM(4));
    M2_TILE(2, 1, WAITVM(4));
  }

  // switch staging to expert region (staged tiles 128.. read H_exp + W3[e])
  srcA0 = (const char*)Hbuf + (size_t)(NTOK + pb + rcj[0]) * (INTER * 2) + gch;
  srcA1 = (const char*)Hbuf + (size_t)(NTOK + pb + rcj[1]) * (INTER * 2) + gch;
  srcB0 = (const char*)Wb + ((size_t)(19 + g) * 1024 + pp * 128) * 8192 + w * 2048 + (lane << 4);

  // ---- K-phase 2: tiles 126..251 (stage 128..253) ----
  for (int r = 0; r < 42; ++r) {
    M2_TILE(0, 1, WAITVM(4));
    M2_TILE(1, 1, WAITVM(4));
    M2_TILE(2, 1, WAITVM(4));
  }
  M2_TILE(0, 1, WAITVM(4));   // t=252 (stages 254)
  M2_TILE(1, 1, WAITVM(4));   // t=253 (stages 255)
  M2_TILE(2, 0, WAITVM(0));   // t=254 (drain)
  M2_TILE(0, 0, (void)0);     // t=255

  // epilogue: single direct write (shared + expert already summed in acc)
  #pragma unroll
  for (int mi = 0; mi < 4; ++mi) {
    #pragma unroll
    for (int j = 0; j < 4; ++j) {
      int r = mw * 64 + mi * 16 + q * 4 + j;
      if (r < rows) {
        int tok = perm[pb + r];
        size_t ob = (size_t)tok * HIDDEN + nbase + nw * 64;
        #pragma unroll
        for (int ni = 0; ni < 4; ++ni)
          __builtin_nontemporal_store(acc[mi][ni][j], &out[ob + ni * 16 + rl]);
      }
    }
  }
}

// ---------------- launcher ----------------

extern "C" void kernel_launch(void* const* d_in, const int* in_sizes, int n_in,
                              void* d_out, int out_size, void* d_ws, size_t ws_size,
                              hipStream_t stream) {
  const float* x   = (const float*)d_in[0];
  const float* w1s = (const float*)d_in[1];
  const float* w2s = (const float*)d_in[2];
  const float* w3s = (const float*)d_in[3];
  const float* W1  = (const float*)d_in[4];
  const float* W2  = (const float*)d_in[5];
  const float* W3  = (const float*)d_in[6];
  const float* Wg  = (const float*)d_in[7];
  float* out = (float*)d_out;

  char* ws = (char*)d_ws;
  size_t o_xb   = 0;
  size_t o_H    = o_xb   + (size_t)NTOK * HIDDEN * 2;           // 8 MB
  size_t o_Wb   = o_H    + (size_t)HROWS * INTER * 2;           // +64 MB
  size_t o_idx  = o_Wb   + (size_t)NMAT * 1024 * 8192;          // +216 MB
  size_t o_perm = o_idx  + (size_t)NTOK * 4;
  size_t o_cnt  = o_perm + (size_t)NTOK * 4;                    // cnt[8]
  size_t o_fill = o_cnt  + 32;                                  // fill[8]
  size_t need   = o_fill + 32;
  if (ws_size < need) return;  // insufficient scratch

  u16*  xb   = (u16*)(ws + o_xb);
  u16*  Hbuf = (u16*)(ws + o_H);
  u16*  Wb   = (u16*)(ws + o_Wb);
  int*  idx  = (int*)(ws + o_idx);
  int*  perm = (int*)(ws + o_perm);
  int*  cnt  = (int*)(ws + o_cnt);
  int*  fill = (int*)(ws + o_fill);

  hipMemsetAsync(ws + o_cnt, 0, 64, stream);   // zero cnt+fill
  k_pre<<<NMAT * 512 + NTOK / 4, 256, 0, stream>>>(w1s, w2s, w3s, W1, W2, W3, Wb,
                                                   x, Wg, idx, cnt, xb);
  k_scatter<<<NTOK / 256, 256, 0, stream>>>(idx, cnt, fill, perm);
  k_mlp1<<<MAXB * 32, 256, 73728, stream>>>(xb, Wb, perm, cnt, Hbuf);
  k_mlp2<<<MAXB2 * 8, 256, 49152, stream>>>(Hbuf, Wb, perm, cnt, out);
}

// Round 18
// 473.363 us; speedup vs baseline: 1.0507x; 1.0507x over previous
//
#include <hip/hip_runtime.h>
#include <stdint.h>

#define HIDDEN 1024
#define INTER  4096
#define NTOK   4096
#define HROWS  (2*NTOK)
#define MAXB   72            // max 128-row-granularity blocks
#define NMAT   27            // 0..8: w1s,W1[0..7]; 9..17: w2s,W2; 18..26: w3s,W3

typedef unsigned short u16;
typedef unsigned int   u32;
typedef __bf16  bf16x8 __attribute__((ext_vector_type(8)));
typedef float   f32x4  __attribute__((ext_vector_type(4)));
typedef u32     u32x4  __attribute__((ext_vector_type(4)));

#define WAITVM(N) asm volatile("s_waitcnt vmcnt(" #N ")" ::: "memory")

__device__ __forceinline__ void hard_barrier() {
  asm volatile("" ::: "memory");
  __builtin_amdgcn_s_barrier();
  asm volatile("" ::: "memory");
}

__device__ __forceinline__ u16 f2bf(float f) {
  u32 u = __float_as_uint(f);
  u32 r = u + 0x7FFFu + ((u >> 16) & 1u);
  return (u16)(r >> 16);
}

__device__ __forceinline__ u32 cvt_pk_bf16(float lo, float hi) {
  u32 r;
  asm("v_cvt_pk_bf16_f32 %0, %1, %2" : "=v"(r) : "v"(lo), "v"(hi));
  return r;
}

__device__ __forceinline__ void glds16(const void* g, void* l) {
  __builtin_amdgcn_global_load_lds(
      (const __attribute__((address_space(1))) void*)g,
      (__attribute__((address_space(3))) void*)l, 16, 0, 0);
}

__device__ __forceinline__ f32x4 ntload4(const float* p) {
  return __builtin_nontemporal_load((const f32x4*)p);
}

// m204 bijective XCD swizzle: consecutive virt ids -> one XCD's contiguous chunk.
__device__ __forceinline__ int xcd_swz(int orig, int T) {
  int q = T >> 3, r = T & 7;
  int xcd = orig & 7, pos = orig >> 3;
  return (xcd < r ? xcd * (q + 1) : r * (q + 1) + (xcd - r) * q) + pos;
}

// Derive the (g, hrow0, rows, pb) block-table entry for 128-row block bx from cnt[8].
__device__ __forceinline__ void blk_entry(const int* cnts, int bx,
                                          int& g, int& hrow0, int& rows, int& pb) {
  if (bx < 32) { g = 8; hrow0 = bx * 128; rows = 128; pb = 0; return; }
  int b = bx - 32, o = 0; g = -1;
  #pragma unroll
  for (int e = 0; e < 8; ++e) {
    int ne = (cnts[e] + 127) >> 7;
    if (g < 0) {
      if (b < ne) {
        g = e; pb = o + b * 128;
        rows = cnts[e] - b * 128; if (rows > 128) rows = 128;
        hrow0 = NTOK + pb;
      } else b -= ne;
    }
    o += cnts[e];
  }
}

// ---------------- k_pre: weight precvt (blocks < NMAT*512) + gate/x-cvt (rest) ----------
// wcvt: fp32 [K][N] -> bf16 pre-swizzled 8KB BK=32 panels.
// Panel (m, cp, kt): [128 n][32 k] bf16; u16 off n*32 + s*8 + (k&7), slot s holds
// k-chunk (s ^ ((n>>1)&3)). pidx = m*1024 + cp*NKT + kt (w1/w2: NKT=32; w3: NKT=128).
// fp32 reads NONTEMPORAL. Gate blocks run concurrently, hidden under wcvt BW;
// gate x-loads VECTORIZED (f32x4 / ushort4 — G13).

__global__ __launch_bounds__(256) void k_pre(
    const float* __restrict__ w1s, const float* __restrict__ w2s,
    const float* __restrict__ w3s, const float* __restrict__ W1,
    const float* __restrict__ W2,  const float* __restrict__ W3,
    u16* __restrict__ Wb,
    const float* __restrict__ x,   const float* __restrict__ wg,
    int* __restrict__ idx, int* __restrict__ cnt, u16* __restrict__ xb)
{
  __shared__ float tileF[32 * 256];
  int tid = threadIdx.x;

  if (blockIdx.x < NMAT * 512) {
    // ---- weight conversion ----
    int bid = blockIdx.x;
    int m = bid >> 9, pair = bid & 511;
    const float* src; int N, nkt, kt, pp2;
    if (m < 18) {
      N = INTER; nkt = 32;
      int mm = (m < 9) ? m : m - 9;
      const float* sp = (m < 9) ? w1s : w2s;
      const float* ep = (m < 9) ? W1 : W2;
      src = (mm == 0) ? sp : ep + (size_t)(mm - 1) * HIDDEN * INTER;
      kt = pair >> 4; pp2 = pair & 15;
    } else {
      N = HIDDEN; nkt = 128;
      int mm = m - 18;
      src = (mm == 0) ? w3s : W3 + (size_t)(mm - 1) * INTER * HIDDEN;
      kt = pair >> 2; pp2 = pair & 3;
    }

    const float* in0 = src + (size_t)(kt * 32) * N + pp2 * 256;
    #pragma unroll
    for (int i = 0; i < 8; ++i) {
      int f = tid + 256 * i;          // float4 index within 32x256 tile
      int k = f >> 6, c4 = f & 63;
      *(f32x4*)&tileF[k * 256 + c4 * 4] = ntload4(in0 + (size_t)k * N + c4 * 4);
    }
    __syncthreads();

    int p2 = tid >> 7, n = tid & 127;
    int pidx = m * 1024 + (pp2 * 2 + p2) * nkt + kt;
    u16* outp = Wb + (size_t)pidx * 4096 + n * 32;
    #pragma unroll
    for (int s = 0; s < 4; ++s) {
      int k8 = s ^ ((n >> 1) & 3);
      const float* col = &tileF[(k8 * 8) * 256 + p2 * 128 + n];
      u32x4 pk;
      pk.x = cvt_pk_bf16(col[0],    col[256]);
      pk.y = cvt_pk_bf16(col[512],  col[768]);
      pk.z = cvt_pk_bf16(col[1024], col[1280]);
      pk.w = cvt_pk_bf16(col[1536], col[1792]);
      *(u32x4*)(outp + s * 8) = pk;
    }
  } else {
    // ---- gate + x->bf16 (vectorized) ----
    int gb = blockIdx.x - NMAT * 512;
    int wave = tid >> 6, lane = tid & 63;
    int t = gb * 4 + wave;
    if (t >= NTOK) return;
    float acc[8];
    #pragma unroll
    for (int e = 0; e < 8; ++e) acc[e] = 0.f;
    const float* xr = x + (size_t)t * HIDDEN;
    u16* xbr = xb + (size_t)t * HIDDEN;
    #pragma unroll
    for (int it = 0; it < HIDDEN / 4 / 64; ++it) {   // 4 iterations
      int c4i = it * 64 + lane;
      f32x4 xv = *(const f32x4*)(xr + c4i * 4);
      ushort4 o;
      o.x = f2bf(xv.x); o.y = f2bf(xv.y); o.z = f2bf(xv.z); o.w = f2bf(xv.w);
      *(ushort4*)(xbr + c4i * 4) = o;
      const float* wr = wg + (size_t)c4i * 32;       // 4 rows of 8
      #pragma unroll
      for (int u = 0; u < 4; ++u)
        #pragma unroll
        for (int e = 0; e < 8; ++e) acc[e] += xv[u] * wr[u * 8 + e];
    }
    #pragma unroll
    for (int e = 0; e < 8; ++e)
      for (int s = 32; s; s >>= 1) acc[e] += __shfl_xor(acc[e], s);
    if (lane == 0) {
      int best = 0; float bv = acc[0];
      #pragma unroll
      for (int e = 1; e < 8; ++e) if (acc[e] > bv) { bv = acc[e]; best = e; }
      idx[t] = best;
      atomicAdd(&cnt[best], 1);
    }
  }
}

__global__ void k_scatter(const int* __restrict__ idx, const int* __restrict__ cnt,
                          int* __restrict__ fill, int* __restrict__ perm) {
  int t = blockIdx.x * blockDim.x + threadIdx.x;
  if (t >= NTOK) return;
  int e = idx[t];
  int off = 0;
  #pragma unroll
  for (int j = 0; j < 8; ++j) off += (j < e) ? cnt[j] : 0;
  int p = atomicAdd(&fill[e], 1);
  perm[off + p] = t;
}

// ---------------- stage 1: H = gelu(Xg@W1) * (Xg@W2) ----------------
// Best measured structure: 128x(128 dual) tile, 4 waves (2M x 2N), 256 threads,
// BK=32, 3 x 24KB LDS -> 2 blocks/CU, depth-2 prefetch, counted WAITVM(6),
// 1D grid with pp-major XCD swizzle (T1), nontemporal Hbuf stores.
// Block-table entry derived in-kernel from cnt. Per buffer: A [0,8K), B1 [8K,16K), B2 [16K,24K).

#define M1_TILE(B, STG, WN)                                                          \
  do {                                                                               \
    const u16* LA = pAr  + (B) * 12288;                                              \
    const u16* L1 = pBr1 + (B) * 12288;                                              \
    const u16* L2 = pBr2 + (B) * 12288;                                              \
    if (STG) {                                                                       \
      char* Ld = smem + (((B) + 2) % 3) * 24576;                                     \
      glds16(srcA0, Ld + w * 2048);                                                  \
      glds16(srcA1, Ld + w * 2048 + 1024);                                           \
      glds16(srcB1, Ld + 8192 + w * 2048);                                           \
      glds16(srcB1 + 1024, Ld + 8192 + w * 2048 + 1024);                             \
      glds16(srcB2, Ld + 16384 + w * 2048);                                          \
      glds16(srcB2 + 1024, Ld + 16384 + w * 2048 + 1024);                            \
      srcA0 += 64; srcA1 += 64; srcB1 += 8192; srcB2 += 8192;                        \
    }                                                                                \
    bf16x8 af[4], b1[4], b2[4];                                                      \
    _Pragma("unroll")                                                                \
    for (int mi = 0; mi < 4; ++mi) af[mi] = *(const bf16x8*)(LA + mi * 512);         \
    _Pragma("unroll")                                                                \
    for (int ni = 0; ni < 4; ++ni) {                                                 \
      b1[ni] = *(const bf16x8*)(L1 + ni * 512);                                      \
      b2[ni] = *(const bf16x8*)(L2 + ni * 512);                                      \
    }                                                                                \
    __builtin_amdgcn_s_setprio(1);                                                   \
    _Pragma("unroll")                                                                \
    for (int mi = 0; mi < 4; ++mi)                                                   \
      _Pragma("unroll")                                                              \
      for (int ni = 0; ni < 4; ++ni) {                                               \
        acc1[mi][ni] = __builtin_amdgcn_mfma_f32_16x16x32_bf16(af[mi], b1[ni], acc1[mi][ni], 0, 0, 0); \
        acc2[mi][ni] = __builtin_amdgcn_mfma_f32_16x16x32_bf16(af[mi], b2[ni], acc2[mi][ni], 0, 0, 0); \
      }                                                                              \
    __builtin_amdgcn_s_setprio(0);                                                   \
    WN;                                                                              \
    hard_barrier();                                                                  \
  } while (0)

__global__ __launch_bounds__(256, 2) void k_mlp1(
    const u16* __restrict__ xb, const u16* __restrict__ Wb,
    const int* __restrict__ perm, const int* __restrict__ cnt,
    u16* __restrict__ Hbuf)
{
  int cnts[8];
  #pragma unroll
  for (int e = 0; e < 8; ++e) cnts[e] = cnt[e];
  int nb = 32;
  #pragma unroll
  for (int e = 0; e < 8; ++e) nb += (cnts[e] + 127) >> 7;
  int T = nb * 32;
  int lid = blockIdx.x;
  if (lid >= T) return;
  int virt = xcd_swz(lid, T);
  int pp = virt / nb;             // 0..31 (B column-panel)
  int bx = virt - pp * nb;        // row-block

  int g, hrow0, rows, pb;
  blk_entry(cnts, bx, g, hrow0, rows, pb);
  int m1 = (g == 8) ? 0 : 1 + g;
  int nbase = pp * 128;

  extern __shared__ __align__(16) char smem[];
  int tid = threadIdx.x;
  int w = tid >> 6, lane = tid & 63;
  int q = lane >> 4, rl = lane & 15;
  int mw = w >> 1, nw = w & 1;

  int tokj[2];
  #pragma unroll
  for (int j = 0; j < 2; ++j) {
    int r = w * 32 + j * 16 + (lane >> 2);
    int rc = (r < rows) ? r : (rows - 1);
    tokj[j] = (g == 8) ? (hrow0 + rc) : perm[pb + rc];
  }
  int gch = ((lane & 3) ^ ((lane >> 3) & 3)) * 16;   // pre-swizzled A source chunk

  const char* srcA0 = (const char*)xb + (size_t)tokj[0] * 2048 + gch;
  const char* srcA1 = (const char*)xb + (size_t)tokj[1] * 2048 + gch;
  const char* srcB1 = (const char*)Wb + ((size_t)m1 * 1024 + pp * 32) * 8192 + w * 2048 + (lane << 4);
  const char* srcB2 = (const char*)Wb + ((size_t)(m1 + 9) * 1024 + pp * 32) * 8192 + w * 2048 + (lane << 4);

  int co = (q ^ ((rl >> 1) & 3)) * 8;
  const u16* pAr  = (const u16*)smem + (mw * 64 + rl) * 32 + co;
  const u16* pBr1 = (const u16*)smem + 4096 + (nw * 64 + rl) * 32 + co;
  const u16* pBr2 = (const u16*)smem + 8192 + (nw * 64 + rl) * 32 + co;

  f32x4 acc1[4][4], acc2[4][4];
  f32x4 z = {0.f, 0.f, 0.f, 0.f};
  #pragma unroll
  for (int mi = 0; mi < 4; ++mi)
    #pragma unroll
    for (int ni = 0; ni < 4; ++ni) { acc1[mi][ni] = z; acc2[mi][ni] = z; }

  // prologue: stage tiles 0,1 (6 glds/wave each)
  #pragma unroll
  for (int p = 0; p < 2; ++p) {
    char* Ld = smem + p * 24576;
    glds16(srcA0, Ld + w * 2048);
    glds16(srcA1, Ld + w * 2048 + 1024);
    glds16(srcB1, Ld + 8192 + w * 2048);
    glds16(srcB1 + 1024, Ld + 8192 + w * 2048 + 1024);
    glds16(srcB2, Ld + 16384 + w * 2048);
    glds16(srcB2 + 1024, Ld + 16384 + w * 2048 + 1024);
    srcA0 += 64; srcA1 += 64; srcB1 += 8192; srcB2 += 8192;
  }
  WAITVM(6);           // 12 out -> tile 0 complete
  hard_barrier();

  // NT = 32: tiles 0..29 stage(t+2); tail 30,31
  for (int r = 0; r < 10; ++r) {
    M1_TILE(0, 1, WAITVM(6));
    M1_TILE(1, 1, WAITVM(6));
    M1_TILE(2, 1, WAITVM(6));
  }
  M1_TILE(0, 0, WAITVM(0));   // t=30
  M1_TILE(1, 0, (void)0);     // t=31

  #pragma unroll
  for (int mi = 0; mi < 4; ++mi) {
    #pragma unroll
    for (int j = 0; j < 4; ++j) {
      int r = mw * 64 + mi * 16 + q * 4 + j;
      if (r < rows) {
        size_t hb = (size_t)(hrow0 + r) * INTER + nbase + nw * 64;
        #pragma unroll
        for (int ni = 0; ni < 4; ++ni) {
          float h1 = acc1[mi][ni][j];
          float h2 = acc2[mi][ni][j];
          float ge = 0.5f * h1 * (1.0f + erff(h1 * 0.7071067811865476f));
          __builtin_nontemporal_store(f2bf(ge * h2), &Hbuf[hb + ni * 16 + rl]);
        }
      }
    }
  }
}

// ---------------- stage 2: Y = H @ W3 ----------------
// 128x128 tile, 4 waves, 256 threads, BK=32, 3 x 16KB LDS -> 3 blocks/CU,
// 1D grid with pp-major XCD swizzle, nontemporal out/yexp stores.
// Block-table entry derived in-kernel. Per buffer: A [0,8K), B [8K,16K).

#define M2_TILE(B, STG, WN)                                                          \
  do {                                                                               \
    const u16* LA = pAr + (B) * 8192;                                                \
    const u16* LB = pBr + (B) * 8192;                                                \
    if (STG) {                                                                       \
      char* Ld = smem + (((B) + 2) % 3) * 16384;                                     \
      glds16(srcA0, Ld + w * 2048);                                                  \
      glds16(srcA1, Ld + w * 2048 + 1024);                                           \
      glds16(srcB0, Ld + 8192 + w * 2048);                                           \
      glds16(srcB0 + 1024, Ld + 8192 + w * 2048 + 1024);                             \
      srcA0 += 64; srcA1 += 64; srcB0 += 8192;                                       \
    }                                                                                \
    bf16x8 af[4], bf[4];                                                             \
    _Pragma("unroll")                                                                \
    for (int mi = 0; mi < 4; ++mi) af[mi] = *(const bf16x8*)(LA + mi * 512);         \
    _Pragma("unroll")                                                                \
    for (int ni = 0; ni < 4; ++ni) bf[ni] = *(const bf16x8*)(LB + ni * 512);         \
    __builtin_amdgcn_s_setprio(1);                                                   \
    _Pragma("unroll")                                                                \
    for (int mi = 0; mi < 4; ++mi)                                                   \
      _Pragma("unroll")                                                              \
      for (int ni = 0; ni < 4; ++ni)                                                 \
        acc[mi][ni] = __builtin_amdgcn_mfma_f32_16x16x32_bf16(af[mi], bf[ni], acc[mi][ni], 0, 0, 0); \
    __builtin_amdgcn_s_setprio(0);                                                   \
    WN;                                                                              \
    hard_barrier();                                                                  \
  } while (0)

__global__ __launch_bounds__(256, 3) void k_mlp2(
    const u16* __restrict__ Hbuf, const u16* __restrict__ Wb,
    const int* __restrict__ perm, const int* __restrict__ cnt,
    float* __restrict__ out, float* __restrict__ yexp)
{
  int cnts[8];
  #pragma unroll
  for (int e = 0; e < 8; ++e) cnts[e] = cnt[e];
  int nb = 32;
  #pragma unroll
  for (int e = 0; e < 8; ++e) nb += (cnts[e] + 127) >> 7;
  int T = nb * 8;
  int lid = blockIdx.x;
  if (lid >= T) return;
  int virt = xcd_swz(lid, T);
  int pp = virt / nb;             // 0..7
  int bx = virt - pp * nb;

  int g, hrow0, rows, pb;
  blk_entry(cnts, bx, g, hrow0, rows, pb);
  int m3 = (g == 8) ? 18 : 19 + g;
  int nbase = pp * 128;

  extern __shared__ __align__(16) char smem[];
  int tid = threadIdx.x;
  int w = tid >> 6, lane = tid & 63;
  int q = lane >> 4, rl = lane & 15;
  int mw = w >> 1, nw = w & 1;

  int hr[2];
  #pragma unroll
  for (int j = 0; j < 2; ++j) {
    int r = w * 32 + j * 16 + (lane >> 2);
    int rc = (r < rows) ? r : (rows - 1);
    hr[j] = hrow0 + rc;
  }
  int gch = ((lane & 3) ^ ((lane >> 3) & 3)) * 16;

  const char* srcA0 = (const char*)Hbuf + (size_t)hr[0] * (INTER * 2) + gch;
  const char* srcA1 = (const char*)Hbuf + (size_t)hr[1] * (INTER * 2) + gch;
  const char* srcB0 = (const char*)Wb + ((size_t)m3 * 1024 + pp * 128) * 8192 + w * 2048 + (lane << 4);

  int co = (q ^ ((rl >> 1) & 3)) * 8;
  const u16* pAr = (const u16*)smem + (mw * 64 + rl) * 32 + co;
  const u16* pBr = (const u16*)smem + 4096 + (nw * 64 + rl) * 32 + co;

  f32x4 acc[4][4];
  f32x4 z = {0.f, 0.f, 0.f, 0.f};
  #pragma unroll
  for (int mi = 0; mi < 4; ++mi)
    #pragma unroll
    for (int ni = 0; ni < 4; ++ni) acc[mi][ni] = z;

  // prologue: stage tiles 0,1 (4 glds/wave each)
  #pragma unroll
  for (int p = 0; p < 2; ++p) {
    char* Ld = smem + p * 16384;
    glds16(srcA0, Ld + w * 2048);
    glds16(srcA1, Ld + w * 2048 + 1024);
    glds16(srcB0, Ld + 8192 + w * 2048);
    glds16(srcB0 + 1024, Ld + 8192 + w * 2048 + 1024);
    srcA0 += 64; srcA1 += 64; srcB0 += 8192;
  }
  WAITVM(4);           // 8 out -> tile 0 complete
  hard_barrier();

  // NT = 128: tiles 0..125 stage(t+2); tail 126,127
  for (int r = 0; r < 42; ++r) {
    M2_TILE(0, 1, WAITVM(4));
    M2_TILE(1, 1, WAITVM(4));
    M2_TILE(2, 1, WAITVM(4));
  }
  M2_TILE(0, 0, WAITVM(0));   // t=126
  M2_TILE(1, 0, (void)0);     // t=127

  float* dstb = (g == 8) ? out : yexp;
  #pragma unroll
  for (int mi = 0; mi < 4; ++mi) {
    #pragma unroll
    for (int j = 0; j < 4; ++j) {
      int r = mw * 64 + mi * 16 + q * 4 + j;
      if (r < rows) {
        int tok = (g == 8) ? (hrow0 + r) : perm[pb + r];
        size_t ob = (size_t)tok * HIDDEN + nbase + nw * 64;
        #pragma unroll
        for (int ni = 0; ni < 4; ++ni)
          __builtin_nontemporal_store(acc[mi][ni][j], &dstb[ob + ni * 16 + rl]);
      }
    }
  }
}

__global__ void k_add(float* __restrict__ out, const float* __restrict__ yexp, int n4) {
  int i = blockIdx.x * blockDim.x + threadIdx.x;
  if (i >= n4) return;
  f32x4 a = __builtin_nontemporal_load(&((const f32x4*)out)[i]);
  f32x4 b = __builtin_nontemporal_load(&((const f32x4*)yexp)[i]);
  a += b;
  ((f32x4*)out)[i] = a;
}

// ---------------- launcher ----------------

extern "C" void kernel_launch(void* const* d_in, const int* in_sizes, int n_in,
                              void* d_out, int out_size, void* d_ws, size_t ws_size,
                              hipStream_t stream) {
  const float* x   = (const float*)d_in[0];
  const float* w1s = (const float*)d_in[1];
  const float* w2s = (const float*)d_in[2];
  const float* w3s = (const float*)d_in[3];
  const float* W1  = (const float*)d_in[4];
  const float* W2  = (const float*)d_in[5];
  const float* W3  = (const float*)d_in[6];
  const float* Wg  = (const float*)d_in[7];
  float* out = (float*)d_out;

  char* ws = (char*)d_ws;
  size_t o_xb   = 0;
  size_t o_H    = o_xb   + (size_t)NTOK * HIDDEN * 2;           // 8 MB
  size_t o_yexp = o_H    + (size_t)HROWS * INTER * 2;           // +64 MB
  size_t o_Wb   = o_yexp + (size_t)NTOK * HIDDEN * 4;           // +16 MB
  size_t o_idx  = o_Wb   + (size_t)NMAT * 1024 * 8192;          // +216 MB
  size_t o_perm = o_idx  + (size_t)NTOK * 4;
  size_t o_cnt  = o_perm + (size_t)NTOK * 4;                    // cnt[8]
  size_t o_fill = o_cnt  + 32;                                  // fill[8]
  size_t need   = o_fill + 32;
  if (ws_size < need) return;  // insufficient scratch

  u16*  xb   = (u16*)(ws + o_xb);
  u16*  Hbuf = (u16*)(ws + o_H);
  float* yexp = (float*)(ws + o_yexp);
  u16*  Wb   = (u16*)(ws + o_Wb);
  int*  idx  = (int*)(ws + o_idx);
  int*  perm = (int*)(ws + o_perm);
  int*  cnt  = (int*)(ws + o_cnt);
  int*  fill = (int*)(ws + o_fill);

  hipMemsetAsync(ws + o_cnt, 0, 64, stream);   // zero cnt+fill
  k_pre<<<NMAT * 512 + NTOK / 4, 256, 0, stream>>>(w1s, w2s, w3s, W1, W2, W3, Wb,
                                                   x, Wg, idx, cnt, xb);
  k_scatter<<<NTOK / 256, 256, 0, stream>>>(idx, cnt, fill, perm);
  k_mlp1<<<MAXB * 32, 256, 73728, stream>>>(xb, Wb, perm, cnt, Hbuf);
  k_mlp2<<<MAXB * 8, 256, 49152, stream>>>(Hbuf, Wb, perm, cnt, out, yexp);
  k_add<<<(NTOK * HIDDEN / 4) / 256, 256, 0, stream>>>(out, yexp, NTOK * HIDDEN / 4);
}